// Round 2
// baseline (400.893 us; speedup 1.0000x reference)
//
#include <hip/hip_runtime.h>
#include <hip/hip_bf16.h>

#define BQ 4
#define SQ 4096
#define DQ 256
#define N3 768

typedef __attribute__((ext_vector_type(8))) _Float16 f16x8;
typedef __attribute__((ext_vector_type(4))) float f32x4;
typedef __attribute__((ext_vector_type(4))) unsigned int u32x4;

__device__ __forceinline__ short f2h(float f) {
  _Float16 h = (_Float16)f;  // v_cvt_f16_f32, RNE
  union { _Float16 h; short s; } v; v.h = h;
  return v.s;
}

// ---------------- QKV projection: qkv = x @ Wqkv + bqkv ----------------
// M=16384, N=768, K=256.  Writes Q,K row-major fp16 [B*S][256] and V
// transposed fp16 [B][256][4096].
__global__ __launch_bounds__(256) void qkv_kernel(
    const float* __restrict__ x, const float* __restrict__ Wqkv,
    const float* __restrict__ bqkv,
    short* __restrict__ Qb, short* __restrict__ Kb, short* __restrict__ Vt) {
  __shared__ short As[64][72];  // x tile   [m][k], pitch 144B (9*16B -> conflict-free frags)
  __shared__ short Ws[64][72];  // W^T tile [n][k]
  const int t = threadIdx.x;
  const int l = t & 63, w = t >> 6;
  const int lr = l & 15, lg = l >> 4;
  const int Mbase = blockIdx.x * 64;
  const int Nbase = blockIdx.y * 64;

  f32x4 acc[4] = {};
  for (int kit = 0; kit < 4; ++kit) {
    const int k0 = kit * 64;
    // stage x -> fp16 LDS
    {
      const int m = t >> 2, kc = (t & 3) * 16;
      const float* src = x + (size_t)(Mbase + m) * DQ + k0 + kc;
      short tmp[16];
#pragma unroll
      for (int i = 0; i < 16; ++i) tmp[i] = f2h(src[i]);
      *(u32x4*)&As[m][kc] = *(u32x4*)&tmp[0];
      *(u32x4*)&As[m][kc + 8] = *(u32x4*)&tmp[8];
    }
    // stage W transposed -> fp16 LDS
    {
      const int n = t & 63, kc2 = (t >> 6) * 16;
      short tmp[16];
#pragma unroll
      for (int i = 0; i < 16; ++i)
        tmp[i] = f2h(Wqkv[(size_t)(k0 + kc2 + i) * N3 + Nbase + n]);
      *(u32x4*)&Ws[n][kc2] = *(u32x4*)&tmp[0];
      *(u32x4*)&Ws[n][kc2 + 8] = *(u32x4*)&tmp[8];
    }
    __syncthreads();
#pragma unroll
    for (int kk = 0; kk < 2; ++kk) {
      f16x8 af = *(f16x8*)&As[w * 16 + lr][kk * 32 + lg * 8];
#pragma unroll
      for (int nf = 0; nf < 4; ++nf) {
        f16x8 bfr = *(f16x8*)&Ws[nf * 16 + lr][kk * 32 + lg * 8];
        acc[nf] = __builtin_amdgcn_mfma_f32_16x16x32_f16(af, bfr, acc[nf], 0, 0, 0);
      }
    }
    __syncthreads();
  }
  // epilogue: bias, cast, route to Q / K / V^T  (whole block is in one segment)
#pragma unroll
  for (int nf = 0; nf < 4; ++nf) {
    const int col = Nbase + nf * 16 + lr;
    const float bias = bqkv[col];
#pragma unroll
    for (int r = 0; r < 4; ++r) {
      const int row = Mbase + w * 16 + lg * 4 + r;  // = b*S + s
      const short sv = f2h(acc[nf][r] + bias);
      if (col < 256) {
        Qb[(size_t)row * DQ + col] = sv;
      } else if (col < 512) {
        Kb[(size_t)row * DQ + (col - 256)] = sv;
      } else {
        const int b = row >> 12, s = row & 4095;
        Vt[(size_t)(b * 256 + (col - 512)) * SQ + s] = sv;
      }
    }
  }
}

// ---------------- Wcomb = Wproj @ Wfc ; c0 = bproj @ Wfc + bfc ----------------
__global__ void wcomb_kernel(const float* __restrict__ Wproj,
                             const float* __restrict__ bproj,
                             const float* __restrict__ Wfc,
                             const float* __restrict__ bfc,
                             float* __restrict__ Wc) {
  __shared__ float wf[256];
  const int t = threadIdx.x;
  wf[t] = Wfc[t];
  __syncthreads();
  float acc = 0.f;
  for (int j = 0; j < 256; ++j) acc += Wproj[(size_t)t * 256 + j] * wf[j];
  Wc[t] = acc;
  if (t == 0) {
    float c = bfc[0];
    for (int j = 0; j < 256; ++j) c += bproj[j] * wf[j];
    Wc[256] = c;
  }
}

// ---------------- Flash attention + fused (proj@fc) epilogue ----------------
// grid 256 = B * (S/64).  4 waves x 16 q-rows.  KBLK=32.
__global__ __launch_bounds__(256) void attn_kernel(
    const short* __restrict__ Qb, const short* __restrict__ Kb,
    const short* __restrict__ Vt, const float* __restrict__ Wc,
    float* __restrict__ out) {
  __shared__ short KsS[32][264];     // K tile [key][d],   pitch 528B (33*16B)
  __shared__ short VsS[256][40];     // V^T tile [d][key], pitch 80B  (5*16B)
  __shared__ short PsS[4][16][40];   // per-wave P [qrow][key], pitch 80B
  const int t = threadIdx.x;
  const int l = t & 63, w = t >> 6;
  const int lr = l & 15, lg = l >> 4;
  const int bid = blockIdx.x;
  const int b = bid >> 6;
  const int qbase = (bid & 63) * 64;

  // Q fragments in registers: wave's 16 rows x 256 d
  f16x8 qf[8];
  {
    const int qrow = qbase + w * 16 + lr;
    const short* qptr = Qb + (size_t)(b * SQ + qrow) * DQ;
#pragma unroll
    for (int kk = 0; kk < 8; ++kk)
      qf[kk] = *(const f16x8*)(qptr + kk * 32 + lg * 8);
  }

  f32x4 o[16] = {};
  float m[4], lsum[4];
#pragma unroll
  for (int r = 0; r < 4; ++r) { m[r] = -1e30f; lsum[r] = 0.f; }

  for (int kb = 0; kb < SQ / 32; ++kb) {
    // ---- stage K tile (coalesced copy) ----
    {
      const int key = t >> 3, c = t & 7;
      const short* src = Kb + (size_t)(b * SQ + kb * 32 + key) * DQ + c * 32;
      u32x4 v0 = *(const u32x4*)(src);
      u32x4 v1 = *(const u32x4*)(src + 8);
      u32x4 v2 = *(const u32x4*)(src + 16);
      u32x4 v3 = *(const u32x4*)(src + 24);
      short* dst = &KsS[key][c * 32];
      *(u32x4*)(dst) = v0;       *(u32x4*)(dst + 8) = v1;
      *(u32x4*)(dst + 16) = v2;  *(u32x4*)(dst + 24) = v3;
    }
    // ---- stage V^T tile (one d-row per thread) ----
    {
      const short* src = Vt + (size_t)(b * DQ + t) * SQ + kb * 32;
      u32x4 v0 = *(const u32x4*)(src);
      u32x4 v1 = *(const u32x4*)(src + 8);
      u32x4 v2 = *(const u32x4*)(src + 16);
      u32x4 v3 = *(const u32x4*)(src + 24);
      short* dst = &VsS[t][0];
      *(u32x4*)(dst) = v0;       *(u32x4*)(dst + 8) = v1;
      *(u32x4*)(dst + 16) = v2;  *(u32x4*)(dst + 24) = v3;
    }
    __syncthreads();

    // ---- S = Q K^T  (A=Q regs, B=K tile) ----
    f32x4 s0 = {}, s1 = {};
#pragma unroll
    for (int kk = 0; kk < 8; ++kk) {
      f16x8 kf0 = *(const f16x8*)&KsS[lr][kk * 32 + lg * 8];
      f16x8 kf1 = *(const f16x8*)&KsS[16 + lr][kk * 32 + lg * 8];
      s0 = __builtin_amdgcn_mfma_f32_16x16x32_f16(qf[kk], kf0, s0, 0, 0, 0);
      s1 = __builtin_amdgcn_mfma_f32_16x16x32_f16(qf[kk], kf1, s1, 0, 0, 0);
    }

    // ---- online softmax (rows = lg*4+r, keys spread over lanes 0..15) ----
    float mt[4];
#pragma unroll
    for (int r = 0; r < 4; ++r) mt[r] = fmaxf(s0[r], s1[r]);
#pragma unroll
    for (int mask = 1; mask <= 8; mask <<= 1) {
#pragma unroll
      for (int r = 0; r < 4; ++r) mt[r] = fmaxf(mt[r], __shfl_xor(mt[r], mask, 64));
    }

    float p0[4], p1[4], rs[4];
#pragma unroll
    for (int r = 0; r < 4; ++r) {
      const float mn = fmaxf(m[r], mt[r]);
      const float sc = __expf(m[r] - mn);
      m[r] = mn;
      p0[r] = __expf(s0[r] - mn);
      p1[r] = __expf(s1[r] - mn);
      lsum[r] *= sc;
      rs[r] = p0[r] + p1[r];
#pragma unroll
      for (int nb = 0; nb < 16; ++nb) o[nb][r] *= sc;
    }
#pragma unroll
    for (int mask = 1; mask <= 8; mask <<= 1) {
#pragma unroll
      for (int r = 0; r < 4; ++r) rs[r] += __shfl_xor(rs[r], mask, 64);
    }
#pragma unroll
    for (int r = 0; r < 4; ++r) lsum[r] += rs[r];

    // ---- P (C-layout) -> per-wave LDS -> A-frag ----
#pragma unroll
    for (int r = 0; r < 4; ++r) {
      PsS[w][lg * 4 + r][lr] = f2h(p0[r]);
      PsS[w][lg * 4 + r][16 + lr] = f2h(p1[r]);
    }
    f16x8 pf = *(const f16x8*)&PsS[w][lr][lg * 8];

    // ---- O += P @ V  (B = V^T tile rows) ----
#pragma unroll
    for (int nb = 0; nb < 16; ++nb) {
      f16x8 vf = *(const f16x8*)&VsS[nb * 16 + lr][lg * 8];
      o[nb] = __builtin_amdgcn_mfma_f32_16x16x32_f16(pf, vf, o[nb], 0, 0, 0);
    }
    __syncthreads();
  }

  // ---- epilogue: out = (O/l) . Wcomb + c0 ----
  const float c0 = Wc[256];
  float part[4] = {0.f, 0.f, 0.f, 0.f};
#pragma unroll
  for (int nb = 0; nb < 16; ++nb) {
    const float wc = Wc[nb * 16 + lr];
#pragma unroll
    for (int r = 0; r < 4; ++r) part[r] += o[nb][r] * wc;
  }
#pragma unroll
  for (int r = 0; r < 4; ++r) part[r] /= lsum[r];
#pragma unroll
  for (int mask = 1; mask <= 8; mask <<= 1) {
#pragma unroll
    for (int r = 0; r < 4; ++r) part[r] += __shfl_xor(part[r], mask, 64);
  }
  if (lr == 0) {
#pragma unroll
    for (int r = 0; r < 4; ++r)
      out[(size_t)b * SQ + qbase + w * 16 + lg * 4 + r] = part[r] + c0;
  }
}

// ---------------- launch ----------------
extern "C" void kernel_launch(void* const* d_in, const int* in_sizes, int n_in,
                              void* d_out, int out_size, void* d_ws, size_t ws_size,
                              hipStream_t stream) {
  const float* x     = (const float*)d_in[0];
  const float* Wqkv  = (const float*)d_in[1];
  const float* bqkv  = (const float*)d_in[2];
  const float* Wproj = (const float*)d_in[3];
  const float* bproj = (const float*)d_in[4];
  const float* Wfc   = (const float*)d_in[5];
  const float* bfc   = (const float*)d_in[6];
  float* out = (float*)d_out;

  const size_t SEG = (size_t)BQ * SQ * DQ * 2;  // 8 MB per fp16 tensor
  char* wsb = (char*)d_ws;
  short* Qb = (short*)(wsb);
  short* Kb = (short*)(wsb + SEG);
  short* Vt = (short*)(wsb + 2 * SEG);
  float* Wc = (float*)(wsb + 3 * SEG);  // 257 floats

  dim3 g1(256, 12);
  qkv_kernel<<<g1, 256, 0, stream>>>(x, Wqkv, bqkv, Qb, Kb, Vt);
  wcomb_kernel<<<1, 256, 0, stream>>>(Wproj, bproj, Wfc, bfc, Wc);
  attn_kernel<<<256, 256, 0, stream>>>(Qb, Kb, Vt, Wc, out);
}

// Round 3
// 239.692 us; speedup vs baseline: 1.6725x; 1.6725x over previous
//
#include <hip/hip_runtime.h>
#include <hip/hip_bf16.h>

#define BQ 4
#define SQ 4096
#define DQ 256
#define N3 768
#define KBLK 64
#define NITER (SQ / KBLK)

typedef __attribute__((ext_vector_type(8))) _Float16 f16x8;
typedef __attribute__((ext_vector_type(4))) float f32x4;
typedef __attribute__((ext_vector_type(4))) unsigned int u32x4;

__device__ __forceinline__ short f2h(float f) {
  _Float16 h = (_Float16)f;  // v_cvt_f16_f32, RNE
  union { _Float16 h; short s; } v; v.h = h;
  return v.s;
}

// ---------------- QKV projection: qkv = x @ Wqkv + bqkv ----------------
__global__ __launch_bounds__(256) void qkv_kernel(
    const float* __restrict__ x, const float* __restrict__ Wqkv,
    const float* __restrict__ bqkv,
    short* __restrict__ Qb, short* __restrict__ Kb, short* __restrict__ Vt) {
  __shared__ short As[64][72];
  __shared__ short Ws[64][72];
  const int t = threadIdx.x;
  const int l = t & 63, w = t >> 6;
  const int lr = l & 15, lg = l >> 4;
  const int Mbase = blockIdx.x * 64;
  const int Nbase = blockIdx.y * 64;

  f32x4 acc[4] = {};
  for (int kit = 0; kit < 4; ++kit) {
    const int k0 = kit * 64;
    {
      const int m = t >> 2, kc = (t & 3) * 16;
      const float* src = x + (size_t)(Mbase + m) * DQ + k0 + kc;
      short tmp[16];
#pragma unroll
      for (int i = 0; i < 16; ++i) tmp[i] = f2h(src[i]);
      *(u32x4*)&As[m][kc] = *(u32x4*)&tmp[0];
      *(u32x4*)&As[m][kc + 8] = *(u32x4*)&tmp[8];
    }
    {
      const int n = t & 63, kc2 = (t >> 6) * 16;
      short tmp[16];
#pragma unroll
      for (int i = 0; i < 16; ++i)
        tmp[i] = f2h(Wqkv[(size_t)(k0 + kc2 + i) * N3 + Nbase + n]);
      *(u32x4*)&Ws[n][kc2] = *(u32x4*)&tmp[0];
      *(u32x4*)&Ws[n][kc2 + 8] = *(u32x4*)&tmp[8];
    }
    __syncthreads();
#pragma unroll
    for (int kk = 0; kk < 2; ++kk) {
      f16x8 af = *(f16x8*)&As[w * 16 + lr][kk * 32 + lg * 8];
#pragma unroll
      for (int nf = 0; nf < 4; ++nf) {
        f16x8 bfr = *(f16x8*)&Ws[nf * 16 + lr][kk * 32 + lg * 8];
        acc[nf] = __builtin_amdgcn_mfma_f32_16x16x32_f16(af, bfr, acc[nf], 0, 0, 0);
      }
    }
    __syncthreads();
  }
#pragma unroll
  for (int nf = 0; nf < 4; ++nf) {
    const int col = Nbase + nf * 16 + lr;
    const float bias = bqkv[col];
#pragma unroll
    for (int r = 0; r < 4; ++r) {
      const int row = Mbase + w * 16 + lg * 4 + r;
      const short sv = f2h(acc[nf][r] + bias);
      if (col < 256) {
        Qb[(size_t)row * DQ + col] = sv;
      } else if (col < 512) {
        Kb[(size_t)row * DQ + (col - 256)] = sv;
      } else {
        const int b = row >> 12, s = row & 4095;
        Vt[(size_t)(b * 256 + (col - 512)) * SQ + s] = sv;
      }
    }
  }
}

// ---------------- Wcomb = Wproj @ Wfc ; c0 = bproj @ Wfc + bfc ----------------
__global__ void wcomb_kernel(const float* __restrict__ Wproj,
                             const float* __restrict__ bproj,
                             const float* __restrict__ Wfc,
                             const float* __restrict__ bfc,
                             float* __restrict__ Wc) {
  __shared__ float wf[256];
  const int t = threadIdx.x;
  wf[t] = Wfc[t];
  __syncthreads();
  float acc = 0.f;
  for (int j = 0; j < 256; ++j) acc += Wproj[(size_t)t * 256 + j] * wf[j];
  Wc[t] = acc;
  if (t == 0) {
    float c = bfc[0];
    for (int j = 0; j < 256; ++j) c += bproj[j] * wf[j];
    Wc[256] = c;
  }
}

// ---------------- Flash attention + fused (proj@fc) epilogue ----------------
// grid 512 = B * (S/32).  4 waves: q-group g = w&1 (16 rows), key-half h = w>>1.
// Each wave: independent online softmax over its 32-key half of each 64-key
// tile; halves merged at the end via (m, l, part) scalars (epilogue is linear).
__global__ __launch_bounds__(256, 2) void attn_kernel(
    const short* __restrict__ Qb, const short* __restrict__ Kb,
    const short* __restrict__ Vt, const float* __restrict__ Wc,
    float* __restrict__ out) {
  __shared__ short KsS[64][264];     // K tile [key][d],   pitch 528B (33*16B)
  __shared__ short VsS[256][72];     // V^T tile [d][key], pitch 144B (9*16B)
  __shared__ short PsS[4][16][40];   // per-wave P [qrow][key], pitch 80B
  __shared__ float Mrg[2][2][16][4]; // [h][g][row]{m,l,part}
  const int t = threadIdx.x;
  const int l = t & 63, w = t >> 6;
  const int lr = l & 15, lg = l >> 4;
  const int g = w & 1, h = w >> 1;
  const int bid = blockIdx.x;
  const int b = bid >> 7;
  const int qbase = (bid & 127) * 32;

  // Q fragments in registers: wave's 16 rows x 256 d
  f16x8 qf[8];
  {
    const short* qptr = Qb + (size_t)(b * SQ + qbase + g * 16 + lr) * DQ;
#pragma unroll
    for (int kk = 0; kk < 8; ++kk)
      qf[kk] = *(const f16x8*)(qptr + kk * 32 + lg * 8);
  }

  const short* kbase = Kb + (size_t)b * SQ * DQ;
  const short* vbase = Vt + (size_t)b * DQ * SQ;

  u32x4 kreg[8], vreg[8];

#define LOADK(KB)                                                        \
  {                                                                      \
    const short* src = kbase + (size_t)(KB) * (KBLK * DQ);               \
    _Pragma("unroll") for (int i = 0; i < 8; ++i)                        \
        kreg[i] = *(const u32x4*)(src + i * 2048 + t * 8);               \
  }
#define LOADV(KB)                                                        \
  {                                                                      \
    _Pragma("unroll") for (int i = 0; i < 2; ++i) {                      \
      const short* src =                                                 \
          vbase + (size_t)(i * 128 + (t >> 1)) * SQ + (KB)*KBLK + (t & 1) * 32; \
      _Pragma("unroll") for (int j = 0; j < 4; ++j)                      \
          vreg[i * 4 + j] = *(const u32x4*)(src + j * 8);                \
    }                                                                    \
  }

  f32x4 o[16] = {};
  float m[4], lsum[4];
#pragma unroll
  for (int r = 0; r < 4; ++r) { m[r] = -1e30f; lsum[r] = 0.f; }

  LOADK(0); LOADV(0);

  for (int kb = 0; kb < NITER; ++kb) {
    // write staged regs -> LDS
#pragma unroll
    for (int i = 0; i < 8; ++i)
      *(u32x4*)&KsS[i * 8 + (t >> 5)][(t & 31) * 8] = kreg[i];
#pragma unroll
    for (int i = 0; i < 2; ++i)
#pragma unroll
      for (int j = 0; j < 4; ++j)
        *(u32x4*)&VsS[i * 128 + (t >> 1)][(t & 1) * 32 + j * 8] = vreg[i * 4 + j];
    __syncthreads();

    // prefetch next tile into regs (latency hides under compute below)
    if (kb + 1 < NITER) { LOADK(kb + 1); LOADV(kb + 1); }

    // ---- S = Q K^T on this wave's 32-key half ----
    f32x4 s0 = {}, s1 = {};
#pragma unroll
    for (int kk = 0; kk < 8; ++kk) {
      f16x8 kf0 = *(const f16x8*)&KsS[h * 32 + lr][kk * 32 + lg * 8];
      f16x8 kf1 = *(const f16x8*)&KsS[h * 32 + 16 + lr][kk * 32 + lg * 8];
      s0 = __builtin_amdgcn_mfma_f32_16x16x32_f16(qf[kk], kf0, s0, 0, 0, 0);
      s1 = __builtin_amdgcn_mfma_f32_16x16x32_f16(qf[kk], kf1, s1, 0, 0, 0);
    }

    // ---- online softmax (defer-max, THR=8) ----
    float mt[4];
#pragma unroll
    for (int r = 0; r < 4; ++r) mt[r] = fmaxf(s0[r], s1[r]);
#pragma unroll
    for (int mask = 1; mask <= 8; mask <<= 1) {
#pragma unroll
      for (int r = 0; r < 4; ++r) mt[r] = fmaxf(mt[r], __shfl_xor(mt[r], mask, 64));
    }
    bool need = false;
#pragma unroll
    for (int r = 0; r < 4; ++r) need = need || (mt[r] > m[r] + 8.f);
    if (__any(need)) {
#pragma unroll
      for (int r = 0; r < 4; ++r) {
        const float mn = fmaxf(m[r], mt[r]);
        const float sc = __expf(m[r] - mn);
        m[r] = mn;
        lsum[r] *= sc;
#pragma unroll
        for (int nb = 0; nb < 16; ++nb) o[nb][r] *= sc;
      }
    }
    float p0[4], p1[4], rs[4];
#pragma unroll
    for (int r = 0; r < 4; ++r) {
      p0[r] = __expf(s0[r] - m[r]);
      p1[r] = __expf(s1[r] - m[r]);
      rs[r] = p0[r] + p1[r];
    }
#pragma unroll
    for (int mask = 1; mask <= 8; mask <<= 1) {
#pragma unroll
      for (int r = 0; r < 4; ++r) rs[r] += __shfl_xor(rs[r], mask, 64);
    }
#pragma unroll
    for (int r = 0; r < 4; ++r) lsum[r] += rs[r];

    // ---- P (C-layout) -> per-wave LDS -> A-frag ----
#pragma unroll
    for (int r = 0; r < 4; ++r) {
      PsS[w][lg * 4 + r][lr] = f2h(p0[r]);
      PsS[w][lg * 4 + r][16 + lr] = f2h(p1[r]);
    }
    f16x8 pf = *(const f16x8*)&PsS[w][lr][lg * 8];

    // ---- O += P @ V on this wave's key half ----
#pragma unroll
    for (int nb = 0; nb < 16; ++nb) {
      f16x8 vf = *(const f16x8*)&VsS[nb * 16 + lr][h * 32 + lg * 8];
      o[nb] = __builtin_amdgcn_mfma_f32_16x16x32_f16(pf, vf, o[nb], 0, 0, 0);
    }
    __syncthreads();
  }

  // ---- epilogue: part = O . Wcomb (linear, so halves merge as scalars) ----
  const float c0 = Wc[256];
  float part[4] = {0.f, 0.f, 0.f, 0.f};
#pragma unroll
  for (int nb = 0; nb < 16; ++nb) {
    const float wc = Wc[nb * 16 + lr];
#pragma unroll
    for (int r = 0; r < 4; ++r) part[r] += o[nb][r] * wc;
  }
#pragma unroll
  for (int mask = 1; mask <= 8; mask <<= 1) {
#pragma unroll
    for (int r = 0; r < 4; ++r) part[r] += __shfl_xor(part[r], mask, 64);
  }

  if (lr == 0) {
#pragma unroll
    for (int r = 0; r < 4; ++r) {
      Mrg[h][g][lg * 4 + r][0] = m[r];
      Mrg[h][g][lg * 4 + r][1] = lsum[r];
      Mrg[h][g][lg * 4 + r][2] = part[r];
    }
  }
  __syncthreads();
  if (h == 0) {
#pragma unroll
    for (int r = 0; r < 4; ++r) {
      const int row = lg * 4 + r;
      const float m2 = Mrg[1][g][row][0];
      const float l2 = Mrg[1][g][row][1];
      const float p2 = Mrg[1][g][row][2];
      const float M = fmaxf(m[r], m2);
      const float e1 = __expf(m[r] - M), e2 = __expf(m2 - M);
      const float lt = e1 * lsum[r] + e2 * l2;
      const float pt = e1 * part[r] + e2 * p2;
      if (lr == 0) out[(size_t)b * SQ + qbase + g * 16 + row] = pt / lt + c0;
    }
  }
}

// ---------------- launch ----------------
extern "C" void kernel_launch(void* const* d_in, const int* in_sizes, int n_in,
                              void* d_out, int out_size, void* d_ws, size_t ws_size,
                              hipStream_t stream) {
  const float* x     = (const float*)d_in[0];
  const float* Wqkv  = (const float*)d_in[1];
  const float* bqkv  = (const float*)d_in[2];
  const float* Wproj = (const float*)d_in[3];
  const float* bproj = (const float*)d_in[4];
  const float* Wfc   = (const float*)d_in[5];
  const float* bfc   = (const float*)d_in[6];
  float* out = (float*)d_out;

  const size_t SEG = (size_t)BQ * SQ * DQ * 2;  // 8 MB per fp16 tensor
  char* wsb = (char*)d_ws;
  short* Qb = (short*)(wsb);
  short* Kb = (short*)(wsb + SEG);
  short* Vt = (short*)(wsb + 2 * SEG);
  float* Wc = (float*)(wsb + 3 * SEG);  // 257 floats

  dim3 g1(256, 12);
  qkv_kernel<<<g1, 256, 0, stream>>>(x, Wqkv, bqkv, Qb, Kb, Vt);
  wcomb_kernel<<<1, 256, 0, stream>>>(Wproj, bproj, Wfc, bfc, Wc);
  attn_kernel<<<512, 256, 0, stream>>>(Qb, Kb, Vt, Wc, out);
}